// Round 3
// baseline (817.871 us; speedup 1.0000x reference)
//
#include <hip/hip_runtime.h>
#include <math.h>

#define BATCH 8
#define NSEQ  1024
#define DIMC  512
#define HEADS 16
#define HD    32
#define TBLN  3969
#define QROWS (BATCH*HEADS*NSEQ)   // 131072 rows of q (and of k)

// ---------------------------------------------------------------------------
// GEMM Y = A @ W^T + bias.  A:[M][K] row-major, W:[N][K] row-major.
// 128x128 block tile, BK=16, 256 threads, 8x8 micro-tile split as 2x2 of 4x4
// (offsets {0,64}) so LDS reads are stride-4-float -> 2-way conflicts (free).
// ---------------------------------------------------------------------------

// epilogue variant 1: scatter into q/k/v [B][H][N][HD]
__global__ __launch_bounds__(256) void gemm_qkv_kernel(
    const float* __restrict__ A, const float* __restrict__ W,
    const float* __restrict__ bias,
    float* __restrict__ qb, float* __restrict__ kb, float* __restrict__ vb)
{
  const int K = DIMC;
  __shared__ float As[16][136];   // [kk][row], stride 136 floats = 16B-aligned rows
  __shared__ float Bs[16][136];
  const int tid = threadIdx.x;
  const int tx = tid & 15, ty = tid >> 4;
  const int r0 = tid >> 2;          // 0..63
  const int lc = (tid & 3) * 4;     // 0,4,8,12
  const int rowBase = blockIdx.y * 128;
  const int colBase = blockIdx.x * 128;

  const float* Ap = A + (size_t)(rowBase + r0) * K + lc;
  const float* Wp = W + (size_t)(colBase + r0) * K + lc;

  float acc[8][8];
#pragma unroll
  for (int i = 0; i < 8; ++i)
#pragma unroll
    for (int j = 0; j < 8; ++j) acc[i][j] = 0.f;

  for (int k0 = 0; k0 < K; k0 += 16) {
    float4 a0 = *(const float4*)(Ap + k0);
    float4 a1 = *(const float4*)(Ap + k0 + (size_t)64 * K);
    float4 w0 = *(const float4*)(Wp + k0);
    float4 w1 = *(const float4*)(Wp + k0 + (size_t)64 * K);
    __syncthreads();
    As[lc+0][r0]    = a0.x; As[lc+1][r0]    = a0.y; As[lc+2][r0]    = a0.z; As[lc+3][r0]    = a0.w;
    As[lc+0][r0+64] = a1.x; As[lc+1][r0+64] = a1.y; As[lc+2][r0+64] = a1.z; As[lc+3][r0+64] = a1.w;
    Bs[lc+0][r0]    = w0.x; Bs[lc+1][r0]    = w0.y; Bs[lc+2][r0]    = w0.z; Bs[lc+3][r0]    = w0.w;
    Bs[lc+0][r0+64] = w1.x; Bs[lc+1][r0+64] = w1.y; Bs[lc+2][r0+64] = w1.z; Bs[lc+3][r0+64] = w1.w;
    __syncthreads();
#pragma unroll
    for (int kk = 0; kk < 16; ++kk) {
      float4 a0v = *(const float4*)&As[kk][ty*4];
      float4 a1v = *(const float4*)&As[kk][ty*4+64];
      float4 b0v = *(const float4*)&Bs[kk][tx*4];
      float4 b1v = *(const float4*)&Bs[kk][tx*4+64];
      float av[8] = {a0v.x,a0v.y,a0v.z,a0v.w,a1v.x,a1v.y,a1v.z,a1v.w};
      float bv[8] = {b0v.x,b0v.y,b0v.z,b0v.w,b1v.x,b1v.y,b1v.z,b1v.w};
#pragma unroll
      for (int i = 0; i < 8; ++i)
#pragma unroll
        for (int j = 0; j < 8; ++j)
          acc[i][j] = fmaf(av[i], bv[j], acc[i][j]);
    }
  }
#pragma unroll
  for (int i = 0; i < 8; ++i) {
    int r = rowBase + ((i < 4) ? (ty*4 + i) : (64 + ty*4 + i - 4));
    int b = r >> 10, n = r & 1023;
#pragma unroll
    for (int j = 0; j < 8; ++j) {
      int c = colBase + ((j < 4) ? (tx*4 + j) : (64 + tx*4 + j - 4));
      float val = acc[i][j] + bias[c];
      int which = c >> 9;           // 0=q 1=k 2=v  (tile never straddles: 64|512)
      int rem = c & 511;
      int h = rem >> 5, d = rem & 31;
      float* dst = (which == 0) ? qb : (which == 1) ? kb : vb;
      dst[(((size_t)b * HEADS + h) * NSEQ + n) * HD + d] = val;
    }
  }
}

// epilogue variant 2: plain write, used for the output projection
__global__ __launch_bounds__(256) void gemm_proj_kernel(
    const float* __restrict__ A, const float* __restrict__ W,
    const float* __restrict__ bias, float* __restrict__ out)
{
  const int K = DIMC;
  __shared__ float As[16][136];
  __shared__ float Bs[16][136];
  const int tid = threadIdx.x;
  const int tx = tid & 15, ty = tid >> 4;
  const int r0 = tid >> 2;
  const int lc = (tid & 3) * 4;
  const int rowBase = blockIdx.y * 128;
  const int colBase = blockIdx.x * 128;

  const float* Ap = A + (size_t)(rowBase + r0) * K + lc;
  const float* Wp = W + (size_t)(colBase + r0) * K + lc;

  float acc[8][8];
#pragma unroll
  for (int i = 0; i < 8; ++i)
#pragma unroll
    for (int j = 0; j < 8; ++j) acc[i][j] = 0.f;

  for (int k0 = 0; k0 < K; k0 += 16) {
    float4 a0 = *(const float4*)(Ap + k0);
    float4 a1 = *(const float4*)(Ap + k0 + (size_t)64 * K);
    float4 w0 = *(const float4*)(Wp + k0);
    float4 w1 = *(const float4*)(Wp + k0 + (size_t)64 * K);
    __syncthreads();
    As[lc+0][r0]    = a0.x; As[lc+1][r0]    = a0.y; As[lc+2][r0]    = a0.z; As[lc+3][r0]    = a0.w;
    As[lc+0][r0+64] = a1.x; As[lc+1][r0+64] = a1.y; As[lc+2][r0+64] = a1.z; As[lc+3][r0+64] = a1.w;
    Bs[lc+0][r0]    = w0.x; Bs[lc+1][r0]    = w0.y; Bs[lc+2][r0]    = w0.z; Bs[lc+3][r0]    = w0.w;
    Bs[lc+0][r0+64] = w1.x; Bs[lc+1][r0+64] = w1.y; Bs[lc+2][r0+64] = w1.z; Bs[lc+3][r0+64] = w1.w;
    __syncthreads();
#pragma unroll
    for (int kk = 0; kk < 16; ++kk) {
      float4 a0v = *(const float4*)&As[kk][ty*4];
      float4 a1v = *(const float4*)&As[kk][ty*4+64];
      float4 b0v = *(const float4*)&Bs[kk][tx*4];
      float4 b1v = *(const float4*)&Bs[kk][tx*4+64];
      float av[8] = {a0v.x,a0v.y,a0v.z,a0v.w,a1v.x,a1v.y,a1v.z,a1v.w};
      float bv[8] = {b0v.x,b0v.y,b0v.z,b0v.w,b1v.x,b1v.y,b1v.z,b1v.w};
#pragma unroll
      for (int i = 0; i < 8; ++i)
#pragma unroll
        for (int j = 0; j < 8; ++j)
          acc[i][j] = fmaf(av[i], bv[j], acc[i][j]);
    }
  }
#pragma unroll
  for (int i = 0; i < 8; ++i) {
    int r = rowBase + ((i < 4) ? (ty*4 + i) : (64 + ty*4 + i - 4));
#pragma unroll
    for (int j = 0; j < 8; ++j) {
      int c = colBase + ((j < 4) ? (tx*4 + j) : (64 + tx*4 + j - 4));
      out[(size_t)r * DIMC + c] = acc[i][j] + bias[c];
    }
  }
}

// ---------------------------------------------------------------------------
// CPB MLP: t[tbl][h] = relu(coords @ fc1^T + b1) @ fc2^T + b2, stored
// transposed tT[h][tbl] for the per-head gather in attention.
// ---------------------------------------------------------------------------
__global__ __launch_bounds__(256) void cpb_kernel(
    const float* __restrict__ table,   // [TBLN][2]
    const float* __restrict__ fc1w,    // [512][2]
    const float* __restrict__ fc1b,    // [512]
    const float* __restrict__ fc2w,    // [16][512]
    const float* __restrict__ fc2b,    // [16]
    float* __restrict__ tT)            // [16][TBLN]
{
  const int row = blockIdx.x;
  const float c0 = table[row*2], c1 = table[row*2+1];
  __shared__ float hid[512];
  __shared__ float red[256];
  const int tid = threadIdx.x;
  for (int j = tid; j < 512; j += 256)
    hid[j] = fmaxf(fmaf(c0, fc1w[j*2], fmaf(c1, fc1w[j*2+1], fc1b[j])), 0.f);
  __syncthreads();
  const int h = tid & 15, part = tid >> 4;     // 16 partial sums of 32 each
  float s = 0.f;
#pragma unroll
  for (int jj = 0; jj < 32; ++jj) {
    int j = part*32 + jj;
    s = fmaf(hid[j], fc2w[h*512 + j], s);
  }
  red[tid] = s;
  __syncthreads();
  if (tid < 16) {
    float t = fc2b[tid];
#pragma unroll
    for (int p = 0; p < 16; ++p) t += red[tid + p*16];
    tT[(size_t)tid * TBLN + row] = t;
  }
}

// ---------------------------------------------------------------------------
// l2-normalize rows of q and k (in place); q additionally gets
// (qn + query_embedding[h]) * softplus(temperature[h]) * seq_length_scale.
// 32 lanes per row (HD=32), one element per thread.
// ---------------------------------------------------------------------------
__global__ __launch_bounds__(256) void norm_kernel(
    float* __restrict__ qb, float* __restrict__ kb,
    const float* __restrict__ temperature,
    const float* __restrict__ qe,      // [HEADS][HD]
    const float* __restrict__ sls)     // scalar
{
  const int gid = blockIdx.x * 256 + threadIdx.x;
  const int lane = gid & 31;
  const int row = gid >> 5;            // 0 .. 2*QROWS-1
  const bool isQ = row < QROWS;
  float* buf = isQ ? qb : kb;
  const int r = isQ ? row : row - QROWS;
  float x = buf[(size_t)r * HD + lane];
  float ss = x * x;
#pragma unroll
  for (int m = 16; m >= 1; m >>= 1) ss += __shfl_xor(ss, m);
  float y = x * (1.f / fmaxf(sqrtf(ss), 1e-12f));
  if (isQ) {
    const int h = (r >> 10) & (HEADS - 1);
    float scale = log1pf(__expf(temperature[h])) * sls[0];
    y = (y + qe[h * HD + lane]) * scale;
  }
  buf[(size_t)r * HD + lane] = y;
}

// ---------------------------------------------------------------------------
// Fused flash-style attention per (b,h). Thread-per-query, 128 queries/block,
// K/V tiles of 32 staged in LDS (all compute reads are lane-broadcast ->
// conflict-free). Bias gathered on the fly: tT[h][rpi[q*1024 + key]].
// ---------------------------------------------------------------------------
#define QPB 128
#define KT  32

__global__ __launch_bounds__(QPB) void attn_kernel(
    const float* __restrict__ qn,   // [B*H][N][HD]
    const float* __restrict__ kn,
    const float* __restrict__ vb,
    const float* __restrict__ tT,   // [16][TBLN]
    const int*   __restrict__ rpi,  // [N*N]
    float* __restrict__ ao)         // [B][N][DIMC]
{
  const int bh = blockIdx.x;            // b*HEADS + h
  const int qt = blockIdx.y;
  const int h  = bh & (HEADS - 1);
  const int b  = bh >> 4;
  const int tid = threadIdx.x;
  const int qi = qt * QPB + tid;

  float qr[HD];
  {
    const float* qrow = qn + ((size_t)bh * NSEQ + qi) * HD;
#pragma unroll
    for (int i = 0; i < 8; ++i) {
      float4 t4 = *(const float4*)&qrow[i*4];
      qr[i*4+0]=t4.x; qr[i*4+1]=t4.y; qr[i*4+2]=t4.z; qr[i*4+3]=t4.w;
    }
  }
  const float* tTh  = tT + (size_t)h * TBLN;
  const int*   rrow = rpi + (size_t)qi * NSEQ;

  __shared__ float ks[KT][HD];
  __shared__ float vs[KT][HD];

  float m = -1e30f, l = 0.f;
  float acc[HD];
#pragma unroll
  for (int d = 0; d < HD; ++d) acc[d] = 0.f;

  for (int kt = 0; kt < NSEQ / KT; ++kt) {
    __syncthreads();
    {
      const float4* ksrc = (const float4*)(kn + ((size_t)bh*NSEQ + kt*KT) * HD);
      const float4* vsrc = (const float4*)(vb + ((size_t)bh*NSEQ + kt*KT) * HD);
      float4* kdst = (float4*)&ks[0][0];
      float4* vdst = (float4*)&vs[0][0];
      kdst[tid]       = ksrc[tid];
      kdst[tid + 128] = ksrc[tid + 128];
      vdst[tid]       = vsrc[tid];
      vdst[tid + 128] = vsrc[tid + 128];
    }
    __syncthreads();

    float s[KT];
#pragma unroll
    for (int j = 0; j < KT; ++j) {
      float as = tTh[rrow[kt*KT + j]];
#pragma unroll
      for (int d = 0; d < HD; ++d) as = fmaf(qr[d], ks[j][d], as);
      s[j] = as;
    }
    float tmax = s[0];
#pragma unroll
    for (int j = 1; j < KT; ++j) tmax = fmaxf(tmax, s[j]);
    float mn = fmaxf(m, tmax);
    float corr = __expf(m - mn);
    m = mn;
    l *= corr;
#pragma unroll
    for (int d = 0; d < HD; ++d) acc[d] *= corr;
#pragma unroll
    for (int j = 0; j < KT; ++j) {
      float p = __expf(s[j] - mn);
      l += p;
#pragma unroll
      for (int d = 0; d < HD; ++d) acc[d] = fmaf(p, vs[j][d], acc[d]);
    }
  }
  const float invl = 1.f / l;
  float* dst = ao + ((size_t)b * NSEQ + qi) * DIMC + h * HD;
#pragma unroll
  for (int i = 0; i < 8; ++i) {
    ((float4*)dst)[i] = make_float4(acc[i*4+0]*invl, acc[i*4+1]*invl,
                                    acc[i*4+2]*invl, acc[i*4+3]*invl);
  }
}

// ---------------------------------------------------------------------------
extern "C" void kernel_launch(void* const* d_in, const int* in_sizes, int n_in,
                              void* d_out, int out_size, void* d_ws, size_t ws_size,
                              hipStream_t stream)
{
  (void)in_sizes; (void)n_in; (void)out_size; (void)ws_size;
  const float* x      = (const float*)d_in[0];
  const float* qkv_w  = (const float*)d_in[1];
  const float* qkv_b  = (const float*)d_in[2];
  const float* proj_w = (const float*)d_in[3];
  const float* proj_b = (const float*)d_in[4];
  const float* temp   = (const float*)d_in[5];
  const float* qe     = (const float*)d_in[6];
  const float* fc1w   = (const float*)d_in[7];
  const float* fc1b   = (const float*)d_in[8];
  const float* fc2w   = (const float*)d_in[9];
  const float* fc2b   = (const float*)d_in[10];
  const float* tbl    = (const float*)d_in[11];
  const int*   rpi    = (const int*)d_in[12];
  const float* sls    = (const float*)d_in[13];
  // d_in[14] padding_mask: all-false and unused by the reference.
  // d_in[15]=H, d_in[16]=W are 32 == trained resolution, so both bilinear
  // resizes are identity; bias[h,n,m] = t[rpi[n*1024+m], h].

  float* ws = (float*)d_ws;
  const size_t perT = (size_t)BATCH * HEADS * NSEQ * HD;   // 4,194,304
  float* qb = ws;
  float* kb = qb + perT;
  float* vb = kb + perT;
  float* tT = vb + perT;                    // HEADS*TBLN = 63,504 floats
  float* ao = tT + (size_t)HEADS * TBLN;    // [B][N][DIMC]

  gemm_qkv_kernel<<<dim3(1536/128, 8192/128), 256, 0, stream>>>(
      x, qkv_w, qkv_b, qb, kb, vb);
  cpb_kernel<<<dim3(TBLN), 256, 0, stream>>>(tbl, fc1w, fc1b, fc2w, fc2b, tT);
  norm_kernel<<<dim3((2*QROWS*32)/256), 256, 0, stream>>>(qb, kb, temp, qe, sls);
  attn_kernel<<<dim3(BATCH*HEADS, NSEQ/QPB), QPB, 0, stream>>>(
      qb, kb, vb, tT, rpi, ao);
  gemm_proj_kernel<<<dim3(512/128, 8192/128), 256, 0, stream>>>(
      ao, proj_w, proj_b, (float*)d_out);
}

// Round 4
// 522.066 us; speedup vs baseline: 1.5666x; 1.5666x over previous
//
#include <hip/hip_runtime.h>
#include <math.h>

#define BATCH 8
#define NSEQ  1024
#define DIMC  512
#define HEADS 16
#define HD    32
#define TBLN  3969
#define QROWS (BATCH*HEADS*NSEQ)

typedef __attribute__((ext_vector_type(8))) short bf16x8;
typedef __attribute__((ext_vector_type(4))) float f32x4;

__device__ __forceinline__ unsigned short f2bf(float f) {
  union { float f; unsigned u; } c; c.f = f;
  unsigned x = c.u + 0x7fffu + ((c.u >> 16) & 1u);   // RNE
  return (unsigned short)(x >> 16);
}
__device__ __forceinline__ float bf2f(unsigned short h) {
  union { unsigned u; float f; } c; c.u = ((unsigned)h) << 16; return c.f;
}

// ---------------------------------------------------------------------------
// fp32 GEMMs (unchanged, proven correct round 3)
// ---------------------------------------------------------------------------
__global__ __launch_bounds__(256) void gemm_qkv_kernel(
    const float* __restrict__ A, const float* __restrict__ W,
    const float* __restrict__ bias,
    float* __restrict__ qb, float* __restrict__ kb, float* __restrict__ vb)
{
  const int K = DIMC;
  __shared__ float As[16][136];
  __shared__ float Bs[16][136];
  const int tid = threadIdx.x;
  const int tx = tid & 15, ty = tid >> 4;
  const int r0 = tid >> 2;
  const int lc = (tid & 3) * 4;
  const int rowBase = blockIdx.y * 128;
  const int colBase = blockIdx.x * 128;
  const float* Ap = A + (size_t)(rowBase + r0) * K + lc;
  const float* Wp = W + (size_t)(colBase + r0) * K + lc;
  float acc[8][8];
#pragma unroll
  for (int i = 0; i < 8; ++i)
#pragma unroll
    for (int j = 0; j < 8; ++j) acc[i][j] = 0.f;
  for (int k0 = 0; k0 < K; k0 += 16) {
    float4 a0 = *(const float4*)(Ap + k0);
    float4 a1 = *(const float4*)(Ap + k0 + (size_t)64 * K);
    float4 w0 = *(const float4*)(Wp + k0);
    float4 w1 = *(const float4*)(Wp + k0 + (size_t)64 * K);
    __syncthreads();
    As[lc+0][r0]    = a0.x; As[lc+1][r0]    = a0.y; As[lc+2][r0]    = a0.z; As[lc+3][r0]    = a0.w;
    As[lc+0][r0+64] = a1.x; As[lc+1][r0+64] = a1.y; As[lc+2][r0+64] = a1.z; As[lc+3][r0+64] = a1.w;
    Bs[lc+0][r0]    = w0.x; Bs[lc+1][r0]    = w0.y; Bs[lc+2][r0]    = w0.z; Bs[lc+3][r0]    = w0.w;
    Bs[lc+0][r0+64] = w1.x; Bs[lc+1][r0+64] = w1.y; Bs[lc+2][r0+64] = w1.z; Bs[lc+3][r0+64] = w1.w;
    __syncthreads();
#pragma unroll
    for (int kk = 0; kk < 16; ++kk) {
      float4 a0v = *(const float4*)&As[kk][ty*4];
      float4 a1v = *(const float4*)&As[kk][ty*4+64];
      float4 b0v = *(const float4*)&Bs[kk][tx*4];
      float4 b1v = *(const float4*)&Bs[kk][tx*4+64];
      float av[8] = {a0v.x,a0v.y,a0v.z,a0v.w,a1v.x,a1v.y,a1v.z,a1v.w};
      float bv[8] = {b0v.x,b0v.y,b0v.z,b0v.w,b1v.x,b1v.y,b1v.z,b1v.w};
#pragma unroll
      for (int i = 0; i < 8; ++i)
#pragma unroll
        for (int j = 0; j < 8; ++j)
          acc[i][j] = fmaf(av[i], bv[j], acc[i][j]);
    }
  }
#pragma unroll
  for (int i = 0; i < 8; ++i) {
    int r = rowBase + ((i < 4) ? (ty*4 + i) : (64 + ty*4 + i - 4));
    int b = r >> 10, n = r & 1023;
#pragma unroll
    for (int j = 0; j < 8; ++j) {
      int c = colBase + ((j < 4) ? (tx*4 + j) : (64 + tx*4 + j - 4));
      float val = acc[i][j] + bias[c];
      int which = c >> 9;
      int rem = c & 511;
      int h = rem >> 5, d = rem & 31;
      float* dst = (which == 0) ? qb : (which == 1) ? kb : vb;
      dst[(((size_t)b * HEADS + h) * NSEQ + n) * HD + d] = val;
    }
  }
}

__global__ __launch_bounds__(256) void gemm_proj_kernel(
    const float* __restrict__ A, const float* __restrict__ W,
    const float* __restrict__ bias, float* __restrict__ out)
{
  const int K = DIMC;
  __shared__ float As[16][136];
  __shared__ float Bs[16][136];
  const int tid = threadIdx.x;
  const int tx = tid & 15, ty = tid >> 4;
  const int r0 = tid >> 2;
  const int lc = (tid & 3) * 4;
  const int rowBase = blockIdx.y * 128;
  const int colBase = blockIdx.x * 128;
  const float* Ap = A + (size_t)(rowBase + r0) * K + lc;
  const float* Wp = W + (size_t)(colBase + r0) * K + lc;
  float acc[8][8];
#pragma unroll
  for (int i = 0; i < 8; ++i)
#pragma unroll
    for (int j = 0; j < 8; ++j) acc[i][j] = 0.f;
  for (int k0 = 0; k0 < K; k0 += 16) {
    float4 a0 = *(const float4*)(Ap + k0);
    float4 a1 = *(const float4*)(Ap + k0 + (size_t)64 * K);
    float4 w0 = *(const float4*)(Wp + k0);
    float4 w1 = *(const float4*)(Wp + k0 + (size_t)64 * K);
    __syncthreads();
    As[lc+0][r0]    = a0.x; As[lc+1][r0]    = a0.y; As[lc+2][r0]    = a0.z; As[lc+3][r0]    = a0.w;
    As[lc+0][r0+64] = a1.x; As[lc+1][r0+64] = a1.y; As[lc+2][r0+64] = a1.z; As[lc+3][r0+64] = a1.w;
    Bs[lc+0][r0]    = w0.x; Bs[lc+1][r0]    = w0.y; Bs[lc+2][r0]    = w0.z; Bs[lc+3][r0]    = w0.w;
    Bs[lc+0][r0+64] = w1.x; Bs[lc+1][r0+64] = w1.y; Bs[lc+2][r0+64] = w1.z; Bs[lc+3][r0+64] = w1.w;
    __syncthreads();
#pragma unroll
    for (int kk = 0; kk < 16; ++kk) {
      float4 a0v = *(const float4*)&As[kk][ty*4];
      float4 a1v = *(const float4*)&As[kk][ty*4+64];
      float4 b0v = *(const float4*)&Bs[kk][tx*4];
      float4 b1v = *(const float4*)&Bs[kk][tx*4+64];
      float av[8] = {a0v.x,a0v.y,a0v.z,a0v.w,a1v.x,a1v.y,a1v.z,a1v.w};
      float bv[8] = {b0v.x,b0v.y,b0v.z,b0v.w,b1v.x,b1v.y,b1v.z,b1v.w};
#pragma unroll
      for (int i = 0; i < 8; ++i)
#pragma unroll
        for (int j = 0; j < 8; ++j)
          acc[i][j] = fmaf(av[i], bv[j], acc[i][j]);
    }
  }
#pragma unroll
  for (int i = 0; i < 8; ++i) {
    int r = rowBase + ((i < 4) ? (ty*4 + i) : (64 + ty*4 + i - 4));
#pragma unroll
    for (int j = 0; j < 8; ++j) {
      int c = colBase + ((j < 4) ? (tx*4 + j) : (64 + tx*4 + j - 4));
      out[(size_t)r * DIMC + c] = acc[i][j] + bias[c];
    }
  }
}

// ---------------------------------------------------------------------------
// CPB MLP (unchanged) -> tT [16][TBLN] f32
// ---------------------------------------------------------------------------
__global__ __launch_bounds__(256) void cpb_kernel(
    const float* __restrict__ table, const float* __restrict__ fc1w,
    const float* __restrict__ fc1b, const float* __restrict__ fc2w,
    const float* __restrict__ fc2b, float* __restrict__ tT)
{
  const int row = blockIdx.x;
  const float c0 = table[row*2], c1 = table[row*2+1];
  __shared__ float hid[512];
  __shared__ float red[256];
  const int tid = threadIdx.x;
  for (int j = tid; j < 512; j += 256)
    hid[j] = fmaxf(fmaf(c0, fc1w[j*2], fmaf(c1, fc1w[j*2+1], fc1b[j])), 0.f);
  __syncthreads();
  const int h = tid & 15, part = tid >> 4;
  float s = 0.f;
#pragma unroll
  for (int jj = 0; jj < 32; ++jj) {
    int j = part*32 + jj;
    s = fmaf(hid[j], fc2w[h*512 + j], s);
  }
  red[tid] = s;
  __syncthreads();
  if (tid < 16) {
    float t = fc2b[tid];
#pragma unroll
    for (int p = 0; p < 16; ++p) t += red[tid + p*16];
    tT[(size_t)tid * TBLN + row] = t;
  }
}

// ---------------------------------------------------------------------------
// rb materialization: rb[h][n][m] = bf16(tT[h][rpi[n*1024+m]]).
// Coalesced rpi read + coalesced rb writes; tT slices are L1/L2 resident.
// ---------------------------------------------------------------------------
__global__ __launch_bounds__(256) void rb_gather_kernel(
    const float* __restrict__ tT, const int* __restrict__ rpi,
    unsigned short* __restrict__ rb)
{
  int gid = blockIdx.x * 256 + threadIdx.x;      // over N*N = 1M (n,m) pairs
  int idx = rpi[gid];
#pragma unroll
  for (int h = 0; h < 16; ++h)
    rb[(size_t)h * NSEQ * NSEQ + gid] = f2bf(tT[h * TBLN + idx]);
}

// ---------------------------------------------------------------------------
// Normalize q,k and emit hi/lo bf16 splits (q post-scale):
// qh+ql ~ fp32 q to 2^-17 rel; same for k. (QK logits are x~29 amplified,
// so plain bf16 would cost ~0.06 logit error -> split is required.)
// ---------------------------------------------------------------------------
__global__ __launch_bounds__(256) void normsplit_kernel(
    const float* __restrict__ qb, const float* __restrict__ kb,
    const float* __restrict__ temperature, const float* __restrict__ qe,
    const float* __restrict__ sls,
    unsigned short* __restrict__ qh, unsigned short* __restrict__ ql,
    unsigned short* __restrict__ kh, unsigned short* __restrict__ kl)
{
  const int gid = blockIdx.x * 256 + threadIdx.x;
  const int lane = gid & 31;
  const int row = gid >> 5;
  const bool isQ = row < QROWS;
  const float* src = isQ ? qb : kb;
  const int r = isQ ? row : row - QROWS;
  float x = src[(size_t)r * HD + lane];
  float ss = x * x;
#pragma unroll
  for (int m = 16; m >= 1; m >>= 1) ss += __shfl_xor(ss, m);
  float y = x / fmaxf(sqrtf(ss), 1e-12f);
  if (isQ) {
    const int h = (r >> 10) & (HEADS - 1);
    float scale = log1pf(__expf(temperature[h])) * sls[0];
    y = (y + qe[h * HD + lane]) * scale;
  }
  unsigned short hi = f2bf(y);
  unsigned short lo = f2bf(y - bf2f(hi));
  size_t idx = (size_t)r * HD + lane;
  if (isQ) { qh[idx] = hi; ql[idx] = lo; }
  else     { kh[idx] = hi; kl[idx] = lo; }
}

// ---------------------------------------------------------------------------
// V transpose: vb f32 [bh][n][32] -> vt bf16 [bh][32][n]. LDS tile, both
// sides coalesced.
// ---------------------------------------------------------------------------
__global__ __launch_bounds__(256) void vt_kernel(
    const float* __restrict__ vb, unsigned short* __restrict__ vt)
{
  __shared__ float tile[32][257];
  const int bh = blockIdx.x, ch = blockIdx.y;   // 256-row chunk
  const int t = threadIdx.x;
  const float* src = vb + ((size_t)bh * NSEQ + ch * 256) * HD;
#pragma unroll
  for (int i = 0; i < 32; ++i) {
    int idx = i * 256 + t;                       // coalesced read
    tile[idx & 31][idx >> 5] = src[idx];
  }
  __syncthreads();
  unsigned short* dst = vt + (size_t)bh * HD * NSEQ + ch * 256;
#pragma unroll
  for (int i = 0; i < 32; ++i) {
    int idx = i * 256 + t;
    int d = idx >> 8, nl = idx & 255;            // coalesced write
    dst[(size_t)d * NSEQ + nl] = f2bf(tile[d][nl]);
  }
}

// ---------------------------------------------------------------------------
// MFMA flash attention. Per wave: 32 queries (two 16-row groups), K-tiles of
// 32 keys. Swapped QK (A=K,B=Q) => D: col=lane&15=q, row=key. K-fragment rows
// are loaded with permutation 8*(v>>2)+(v&3) so the two 16-key D fragments'
// per-lane values are EXACTLY the K=32 PV A-fragment slots (kappa=8*hi+j):
// zero cross-lane movement, zero LDS, zero barriers. QK uses hi/lo split
// (3 MFMA); PV uses bf16 P and bf16 V^T (2 MFMA per group).
// ---------------------------------------------------------------------------
__global__ __launch_bounds__(256, 4) void attn_mfma_kernel(
    const unsigned short* __restrict__ qh, const unsigned short* __restrict__ ql,
    const unsigned short* __restrict__ kh, const unsigned short* __restrict__ kl,
    const unsigned short* __restrict__ vt, const unsigned short* __restrict__ rb,
    float* __restrict__ ao)
{
  const int bh = blockIdx.x;
  const int h = bh & (HEADS - 1), b = bh >> 4;
  const int wave = threadIdx.x >> 6;
  const int lane = threadIdx.x & 63;
  const int l16 = lane & 15, hi4 = lane >> 4;
  const int qbase = blockIdx.y * 128 + wave * 32;

  // loop-invariant q fragments (B-operand): lane holds q[qg+l16][d=8*hi4+j]
  bf16x8 qhf[2], qlf[2];
#pragma unroll
  for (int g = 0; g < 2; ++g) {
    size_t ro = ((size_t)bh * NSEQ + qbase + g * 16 + l16) * HD + hi4 * 8;
    qhf[g] = *(const bf16x8*)(qh + ro);
    qlf[g] = *(const bf16x8*)(ql + ro);
  }

  f32x4 accV[2][2] = {};             // [group][d-subtile]
  float mst[2] = {-INFINITY, -INFINITY};
  float lst[2] = {0.f, 0.f};

  const int krow_p = 8 * (l16 >> 2) + (l16 & 3);   // permuted key row in tile

  for (int kt = 0; kt < NSEQ / 32; ++kt) {
    const int k0 = kt * 32;
    // K fragments (A-operand), permuted rows; subtile1 = +4
    size_t kr0 = ((size_t)bh * NSEQ + k0 + krow_p) * HD + hi4 * 8;
    size_t kr1 = kr0 + 4 * HD;
    bf16x8 kh0 = *(const bf16x8*)(kh + kr0);
    bf16x8 kh1 = *(const bf16x8*)(kh + kr1);
    bf16x8 kl0 = *(const bf16x8*)(kl + kr0);
    bf16x8 kl1 = *(const bf16x8*)(kl + kr1);
    // V^T fragments (PV B-operand): lane holds V[k0+8*hi4+j][d0+l16]
    bf16x8 vt0 = *(const bf16x8*)(vt + ((size_t)bh * HD +  0 + l16) * NSEQ + k0 + hi4 * 8);
    bf16x8 vt1 = *(const bf16x8*)(vt + ((size_t)bh * HD + 16 + l16) * NSEQ + k0 + hi4 * 8);

#pragma unroll
    for (int g = 0; g < 2; ++g) {
      f32x4 D0 = {0.f, 0.f, 0.f, 0.f};
      f32x4 D1 = {0.f, 0.f, 0.f, 0.f};
      // S = kh*qh + kh*ql + kl*qh  (hi/lo split, ~2^-17 rel)
      D0 = __builtin_amdgcn_mfma_f32_16x16x32_bf16(kh0, qhf[g], D0, 0, 0, 0);
      D0 = __builtin_amdgcn_mfma_f32_16x16x32_bf16(kh0, qlf[g], D0, 0, 0, 0);
      D0 = __builtin_amdgcn_mfma_f32_16x16x32_bf16(kl0, qhf[g], D0, 0, 0, 0);
      D1 = __builtin_amdgcn_mfma_f32_16x16x32_bf16(kh1, qhf[g], D1, 0, 0, 0);
      D1 = __builtin_amdgcn_mfma_f32_16x16x32_bf16(kh1, qlf[g], D1, 0, 0, 0);
      D1 = __builtin_amdgcn_mfma_f32_16x16x32_bf16(kl1, qhf[g], D1, 0, 0, 0);

      // bias: lane needs rb[h][q=qg+l16][k0+8*hi4 .. +7] = 16B contiguous
      bf16x8 b8 = *(const bf16x8*)(rb + ((size_t)h * NSEQ + qbase + g * 16 + l16) * NSEQ + k0 + hi4 * 8);

      float sv0[4], sv1[4];
#pragma unroll
      for (int r = 0; r < 4; ++r) {
        sv0[r] = D0[r] + bf2f((unsigned short)b8[r]);      // key 8*hi4+r
        sv1[r] = D1[r] + bf2f((unsigned short)b8[4 + r]);  // key 8*hi4+4+r
      }
      // online softmax over the 4 lanes sharing this q (xor 16, 32)
      float tm = fmaxf(fmaxf(fmaxf(sv0[0], sv0[1]), fmaxf(sv0[2], sv0[3])),
                       fmaxf(fmaxf(sv1[0], sv1[1]), fmaxf(sv1[2], sv1[3])));
      tm = fmaxf(tm, __shfl_xor(tm, 16));
      tm = fmaxf(tm, __shfl_xor(tm, 32));
      float mn = fmaxf(mst[g], tm);
      float corr = __expf(mst[g] - mn);
      mst[g] = mn;
      float p0[4], p1[4], ps = 0.f;
#pragma unroll
      for (int r = 0; r < 4; ++r) {
        p0[r] = __expf(sv0[r] - mn);
        p1[r] = __expf(sv1[r] - mn);
        ps += p0[r] + p1[r];
      }
      ps += __shfl_xor(ps, 16);
      ps += __shfl_xor(ps, 32);
      lst[g] = lst[g] * corr + ps;

      // PV acc lives as D2: col=l16=d, row=4*hi4+r=q -> fetch corr per row-q
      float cA[4];
#pragma unroll
      for (int r = 0; r < 4; ++r) cA[r] = __shfl(corr, hi4 * 4 + r);
#pragma unroll
      for (int r = 0; r < 4; ++r) {
        accV[g][0][r] *= cA[r];
        accV[g][1][r] *= cA[r];
      }
      // P fragment: slots j=0..3 <- D0 regs, j=4..7 <- D1 regs (by design)
      bf16x8 pa;
#pragma unroll
      for (int r = 0; r < 4; ++r) {
        pa[r]     = (short)f2bf(p0[r]);
        pa[4 + r] = (short)f2bf(p1[r]);
      }
      accV[g][0] = __builtin_amdgcn_mfma_f32_16x16x32_bf16(pa, vt0, accV[g][0], 0, 0, 0);
      accV[g][1] = __builtin_amdgcn_mfma_f32_16x16x32_bf16(pa, vt1, accV[g][1], 0, 0, 0);
    }
  }

  // epilogue: out[q = qbase+g*16+4*hi4+r][h*32 + df*16 + l16]
#pragma unroll
  for (int g = 0; g < 2; ++g) {
    float inv = 1.f / lst[g];
    float iA[4];
#pragma unroll
    for (int r = 0; r < 4; ++r) iA[r] = __shfl(inv, hi4 * 4 + r);
#pragma unroll
    for (int df = 0; df < 2; ++df)
#pragma unroll
      for (int r = 0; r < 4; ++r)
        ao[((size_t)b * NSEQ + qbase + g * 16 + hi4 * 4 + r) * DIMC
           + h * HD + df * 16 + l16] = accV[g][df][r] * iA[r];
  }
}

// ---------------------------------------------------------------------------
extern "C" void kernel_launch(void* const* d_in, const int* in_sizes, int n_in,
                              void* d_out, int out_size, void* d_ws, size_t ws_size,
                              hipStream_t stream)
{
  (void)in_sizes; (void)n_in; (void)out_size; (void)ws_size;
  const float* x      = (const float*)d_in[0];
  const float* qkv_w  = (const float*)d_in[1];
  const float* qkv_b  = (const float*)d_in[2];
  const float* proj_w = (const float*)d_in[3];
  const float* proj_b = (const float*)d_in[4];
  const float* temp   = (const float*)d_in[5];
  const float* qe     = (const float*)d_in[6];
  const float* fc1w   = (const float*)d_in[7];
  const float* fc1b   = (const float*)d_in[8];
  const float* fc2w   = (const float*)d_in[9];
  const float* fc2b   = (const float*)d_in[10];
  const float* tbl    = (const float*)d_in[11];
  const int*   rpi    = (const int*)d_in[12];
  const float* sls    = (const float*)d_in[13];
  // H=W=32 == trained resolution: both bilinear resizes are identity;
  // bias[h,n,m] = t[rpi[n*1024+m], h].

  char* ws = (char*)d_ws;
  const size_t perT = (size_t)BATCH * HEADS * NSEQ * HD;    // 4,194,304 elems
  float* qb = (float*)ws;                                   // 16 MB
  float* kb = qb + perT;                                    // 16 MB
  float* vb = kb + perT;                                    // 16 MB
  float* tT = vb + perT;                                    // 256 KB
  float* ao = tT + 65536;                                   // 16 MB
  unsigned short* qh = (unsigned short*)(ao + perT);        // 8 MB
  unsigned short* ql = qh + perT;
  unsigned short* kh = ql + perT;
  unsigned short* kl = kh + perT;
  unsigned short* vt = kl + perT;                           // 8 MB
  // rb bf16 [16][1024][1024] = 32MB ALIASES qb+kb (dead after normsplit)
  unsigned short* rb = (unsigned short*)qb;

  gemm_qkv_kernel<<<dim3(1536/128, 8192/128), 256, 0, stream>>>(
      x, qkv_w, qkv_b, qb, kb, vb);
  cpb_kernel<<<dim3(TBLN), 256, 0, stream>>>(tbl, fc1w, fc1b, fc2w, fc2b, tT);
  normsplit_kernel<<<dim3((2*QROWS*32)/256), 256, 0, stream>>>(
      qb, kb, temp, qe, sls, qh, ql, kh, kl);
  vt_kernel<<<dim3(BATCH*HEADS, NSEQ/256), 256, 0, stream>>>(vb, vt);
  rb_gather_kernel<<<dim3((NSEQ*NSEQ)/256), 256, 0, stream>>>(tT, rpi, rb);
  attn_mfma_kernel<<<dim3(BATCH*HEADS, NSEQ/128), 256, 0, stream>>>(
      qh, ql, kh, kl, vt, rb, ao);
  gemm_proj_kernel<<<dim3(512/128, 8192/128), 256, 0, stream>>>(
      ao, proj_w, proj_b, (float*)d_out);
}

// Round 5
// 380.206 us; speedup vs baseline: 2.1511x; 1.3731x over previous
//
#include <hip/hip_runtime.h>
#include <math.h>

#define BATCH 8
#define NSEQ  1024
#define DIMC  512
#define HEADS 16
#define HD    32
#define TBLN  3969
#define QROWS (BATCH*HEADS*NSEQ)

typedef __attribute__((ext_vector_type(8))) short bf16x8;
typedef __attribute__((ext_vector_type(4))) float f32x4;

__device__ __forceinline__ unsigned short f2bf(float f) {
  union { float f; unsigned u; } c; c.f = f;
  unsigned x = c.u + 0x7fffu + ((c.u >> 16) & 1u);   // RNE
  return (unsigned short)(x >> 16);
}
__device__ __forceinline__ float bf2f(unsigned short h) {
  union { unsigned u; float f; } c; c.u = ((unsigned)h) << 16; return c.f;
}

// ---------------------------------------------------------------------------
// hi/lo bf16 split of an fp32 array (float4 per thread).
// ---------------------------------------------------------------------------
__global__ __launch_bounds__(256) void split_kernel(
    const float* __restrict__ src, unsigned short* __restrict__ hi,
    unsigned short* __restrict__ lo, int n4)
{
  int gid = blockIdx.x * 256 + threadIdx.x;
  if (gid >= n4) return;
  float4 v = ((const float4*)src)[gid];
  float vv[4] = {v.x, v.y, v.z, v.w};
  unsigned short h[4], l[4];
#pragma unroll
  for (int i = 0; i < 4; ++i) {
    h[i] = f2bf(vv[i]);
    l[i] = f2bf(vv[i] - bf2f(h[i]));
  }
  uint2 hp, lp;
  hp.x = h[0] | ((unsigned)h[1] << 16); hp.y = h[2] | ((unsigned)h[3] << 16);
  lp.x = l[0] | ((unsigned)l[1] << 16); lp.y = l[2] | ((unsigned)l[3] << 16);
  ((uint2*)hi)[gid] = hp;
  ((uint2*)lo)[gid] = lp;
}

// ---------------------------------------------------------------------------
// Split-bf16 MFMA GEMM: Y = (Ah+Al)@(Wh+Wl)^T + bias ~ fp32 to 2^-17.
// A:[M][512] W:[N][512] (both row-major over K). 128x128 tile, BK=32,
// 4 waves, 16x16x32 MFMA, 3 MFMAs per fragment pair (split terms).
// Staging: global_load_lds width-16 into 4x8KB LDS tiles, XOR-swizzled
// (slot ^= (row>>1)&3 on 16B slots) via inverse-swizzled GLOBAL source
// (gload_lds writes linearly) + swizzled ds_read -> 2-way conflicts (free).
// EPI 0: scatter into q/k/v [B][H][N][HD]; EPI 1: plain [M][512] write.
// ---------------------------------------------------------------------------
template<int EPI>
__global__ __launch_bounds__(256) void gemm_split_kernel(
    const unsigned short* __restrict__ Ah, const unsigned short* __restrict__ Al,
    const unsigned short* __restrict__ Wh, const unsigned short* __restrict__ Wl,
    const float* __restrict__ bias,
    float* __restrict__ o0p, float* __restrict__ o1p, float* __restrict__ o2p)
{
  const int K = DIMC;
  __shared__ __align__(16) unsigned short lds[4 * 4096];
  unsigned short* ldsAh = lds;
  unsigned short* ldsAl = lds + 4096;
  unsigned short* ldsBh = lds + 8192;
  unsigned short* ldsBl = lds + 12288;
  const int tid = threadIdx.x;
  const int wave = tid >> 6, lane = tid & 63;
  const int l16 = lane & 15, hi4 = lane >> 4;
  const int rowBase = blockIdx.y * 128, colBase = blockIdx.x * 128;
  const int warpRow = (wave >> 1) * 64, warpCol = (wave & 1) * 64;

  // staging geometry: 2 x 1KB issues per wave per tile; linear LDS byte o,
  // global source column pre-inverse-swizzled so swizzled reads see A[row][k].
  const int o0 = wave * 2048 + lane * 16;
  const int o1 = o0 + 1024;
  const int row0 = o0 >> 6, s0 = (o0 >> 4) & 3;
  const int row1 = o1 >> 6, s1 = (o1 >> 4) & 3;
  const int g0 = row0 * K + ((s0 ^ ((row0 >> 1) & 3)) << 3);   // elem offset
  const int g1 = row1 * K + ((s1 ^ ((row1 >> 1) & 3)) << 3);

  const unsigned short* A0h = Ah + (size_t)rowBase * K;
  const unsigned short* A0l = Al + (size_t)rowBase * K;
  const unsigned short* W0h = Wh + (size_t)colBase * K;
  const unsigned short* W0l = Wl + (size_t)colBase * K;

  f32x4 acc[4][4] = {};

  float biasv[4];
#pragma unroll
  for (int fj = 0; fj < 4; ++fj)
    biasv[fj] = bias[colBase + warpCol + fj * 16 + l16];

  // swizzled ds_read byte addrs: row r, kslot hi4 -> slot hi4^((r>>1)&3)
  int ra[4], rbq[4];
#pragma unroll
  for (int f = 0; f < 4; ++f) {
    int rowA = warpRow + f * 16 + l16;
    ra[f] = rowA * 64 + ((hi4 ^ ((rowA >> 1) & 3)) << 4);
    int rowB = warpCol + f * 16 + l16;
    rbq[f] = rowB * 64 + ((hi4 ^ ((rowB >> 1) & 3)) << 4);
  }

#define GLD(gsrc, ldst) __builtin_amdgcn_global_load_lds( \
      (const __attribute__((address_space(1))) unsigned int*)(gsrc), \
      (__attribute__((address_space(3))) unsigned int*)(ldst), 16, 0, 0)

  for (int k0 = 0; k0 < K; k0 += 32) {
    __syncthreads();                       // prev-tile reads complete
    GLD(A0h + k0 + g0, (char*)ldsAh + o0);
    GLD(A0h + k0 + g1, (char*)ldsAh + o1);
    GLD(A0l + k0 + g0, (char*)ldsAl + o0);
    GLD(A0l + k0 + g1, (char*)ldsAl + o1);
    GLD(W0h + k0 + g0, (char*)ldsBh + o0);
    GLD(W0h + k0 + g1, (char*)ldsBh + o1);
    GLD(W0l + k0 + g0, (char*)ldsBl + o0);
    GLD(W0l + k0 + g1, (char*)ldsBl + o1);
    __syncthreads();                       // vmcnt(0) drained by compiler

    bf16x8 a_h[4], a_l[4], b_h[4], b_l[4];
#pragma unroll
    for (int f = 0; f < 4; ++f) {
      a_h[f] = *(const bf16x8*)((const char*)ldsAh + ra[f]);
      a_l[f] = *(const bf16x8*)((const char*)ldsAl + ra[f]);
      b_h[f] = *(const bf16x8*)((const char*)ldsBh + rbq[f]);
      b_l[f] = *(const bf16x8*)((const char*)ldsBl + rbq[f]);
    }
#pragma unroll
    for (int fi = 0; fi < 4; ++fi)
#pragma unroll
      for (int fj = 0; fj < 4; ++fj) {
        acc[fi][fj] = __builtin_amdgcn_mfma_f32_16x16x32_bf16(a_l[fi], b_h[fj], acc[fi][fj], 0, 0, 0);
        acc[fi][fj] = __builtin_amdgcn_mfma_f32_16x16x32_bf16(a_h[fi], b_l[fj], acc[fi][fj], 0, 0, 0);
        acc[fi][fj] = __builtin_amdgcn_mfma_f32_16x16x32_bf16(a_h[fi], b_h[fj], acc[fi][fj], 0, 0, 0);
      }
  }
#undef GLD

  // epilogue: D layout col=lane&15, row=(lane>>4)*4+reg
#pragma unroll
  for (int fi = 0; fi < 4; ++fi)
#pragma unroll
    for (int fj = 0; fj < 4; ++fj)
#pragma unroll
      for (int r = 0; r < 4; ++r) {
        int m = rowBase + warpRow + fi * 16 + hi4 * 4 + r;
        int c = colBase + warpCol + fj * 16 + l16;
        float val = acc[fi][fj][r] + biasv[fj];
        if (EPI == 0) {
          int b = m >> 10, n = m & 1023;
          int which = c >> 9, rem = c & 511;
          int hh = rem >> 5, d = rem & 31;
          float* dst = (which == 0) ? o0p : (which == 1) ? o1p : o2p;
          dst[(((size_t)b * HEADS + hh) * NSEQ + n) * HD + d] = val;
        } else {
          o0p[(size_t)m * DIMC + c] = val;
        }
      }
}

// ---------------------------------------------------------------------------
// CPB MLP (unchanged) -> tT [16][TBLN] f32
// ---------------------------------------------------------------------------
__global__ __launch_bounds__(256) void cpb_kernel(
    const float* __restrict__ table, const float* __restrict__ fc1w,
    const float* __restrict__ fc1b, const float* __restrict__ fc2w,
    const float* __restrict__ fc2b, float* __restrict__ tT)
{
  const int row = blockIdx.x;
  const float c0 = table[row*2], c1 = table[row*2+1];
  __shared__ float hid[512];
  __shared__ float red[256];
  const int tid = threadIdx.x;
  for (int j = tid; j < 512; j += 256)
    hid[j] = fmaxf(fmaf(c0, fc1w[j*2], fmaf(c1, fc1w[j*2+1], fc1b[j])), 0.f);
  __syncthreads();
  const int h = tid & 15, part = tid >> 4;
  float s = 0.f;
#pragma unroll
  for (int jj = 0; jj < 32; ++jj) {
    int j = part*32 + jj;
    s = fmaf(hid[j], fc2w[h*512 + j], s);
  }
  red[tid] = s;
  __syncthreads();
  if (tid < 16) {
    float t = fc2b[tid];
#pragma unroll
    for (int p = 0; p < 16; ++p) t += red[tid + p*16];
    tT[(size_t)tid * TBLN + row] = t;
  }
}

// ---------------------------------------------------------------------------
// rb materialization (unchanged): rb[h][n][m] = bf16(tT[h][rpi[n*1024+m]]).
// ---------------------------------------------------------------------------
__global__ __launch_bounds__(256) void rb_gather_kernel(
    const float* __restrict__ tT, const int* __restrict__ rpi,
    unsigned short* __restrict__ rb)
{
  int gid = blockIdx.x * 256 + threadIdx.x;
  int idx = rpi[gid];
#pragma unroll
  for (int h = 0; h < 16; ++h)
    rb[(size_t)h * NSEQ * NSEQ + gid] = f2bf(tT[h * TBLN + idx]);
}

// ---------------------------------------------------------------------------
// Normalize q,k, emit hi/lo bf16 splits (unchanged).
// ---------------------------------------------------------------------------
__global__ __launch_bounds__(256) void normsplit_kernel(
    const float* __restrict__ qb, const float* __restrict__ kb,
    const float* __restrict__ temperature, const float* __restrict__ qe,
    const float* __restrict__ sls,
    unsigned short* __restrict__ qh, unsigned short* __restrict__ ql,
    unsigned short* __restrict__ kh, unsigned short* __restrict__ kl)
{
  const int gid = blockIdx.x * 256 + threadIdx.x;
  const int lane = gid & 31;
  const int row = gid >> 5;
  const bool isQ = row < QROWS;
  const float* src = isQ ? qb : kb;
  const int r = isQ ? row : row - QROWS;
  float x = src[(size_t)r * HD + lane];
  float ss = x * x;
#pragma unroll
  for (int m = 16; m >= 1; m >>= 1) ss += __shfl_xor(ss, m);
  float y = x / fmaxf(sqrtf(ss), 1e-12f);
  if (isQ) {
    const int h = (r >> 10) & (HEADS - 1);
    float scale = log1pf(__expf(temperature[h])) * sls[0];
    y = (y + qe[h * HD + lane]) * scale;
  }
  unsigned short hi = f2bf(y);
  unsigned short lo = f2bf(y - bf2f(hi));
  size_t idx = (size_t)r * HD + lane;
  if (isQ) { qh[idx] = hi; ql[idx] = lo; }
  else     { kh[idx] = hi; kl[idx] = lo; }
}

// ---------------------------------------------------------------------------
// V transpose (unchanged): vb f32 [bh][n][32] -> vt bf16 [bh][32][n].
// ---------------------------------------------------------------------------
__global__ __launch_bounds__(256) void vt_kernel(
    const float* __restrict__ vb, unsigned short* __restrict__ vt)
{
  __shared__ float tile[32][257];
  const int bh = blockIdx.x, ch = blockIdx.y;
  const int t = threadIdx.x;
  const float* src = vb + ((size_t)bh * NSEQ + ch * 256) * HD;
#pragma unroll
  for (int i = 0; i < 32; ++i) {
    int idx = i * 256 + t;
    tile[idx & 31][idx >> 5] = src[idx];
  }
  __syncthreads();
  unsigned short* dst = vt + (size_t)bh * HD * NSEQ + ch * 256;
#pragma unroll
  for (int i = 0; i < 32; ++i) {
    int idx = i * 256 + t;
    int d = idx >> 8, nl = idx & 255;
    dst[(size_t)d * NSEQ + nl] = f2bf(tile[d][nl]);
  }
}

// ---------------------------------------------------------------------------
// MFMA flash attention (round-4 structure, proven). Epilogue now writes
// hi/lo bf16 (aoh/aol) so gemm_proj consumes split operands directly.
// ---------------------------------------------------------------------------
__global__ __launch_bounds__(256, 4) void attn_mfma_kernel(
    const unsigned short* __restrict__ qh, const unsigned short* __restrict__ ql,
    const unsigned short* __restrict__ kh, const unsigned short* __restrict__ kl,
    const unsigned short* __restrict__ vt, const unsigned short* __restrict__ rb,
    unsigned short* __restrict__ aoh, unsigned short* __restrict__ aol)
{
  const int bh = blockIdx.x;
  const int h = bh & (HEADS - 1), b = bh >> 4;
  const int wave = threadIdx.x >> 6;
  const int lane = threadIdx.x & 63;
  const int l16 = lane & 15, hi4 = lane >> 4;
  const int qbase = blockIdx.y * 128 + wave * 32;

  bf16x8 qhf[2], qlf[2];
#pragma unroll
  for (int g = 0; g < 2; ++g) {
    size_t ro = ((size_t)bh * NSEQ + qbase + g * 16 + l16) * HD + hi4 * 8;
    qhf[g] = *(const bf16x8*)(qh + ro);
    qlf[g] = *(const bf16x8*)(ql + ro);
  }

  f32x4 accV[2][2] = {};
  float mst[2] = {-INFINITY, -INFINITY};
  float lst[2] = {0.f, 0.f};

  const int krow_p = 8 * (l16 >> 2) + (l16 & 3);

  for (int kt = 0; kt < NSEQ / 32; ++kt) {
    const int k0 = kt * 32;
    size_t kr0 = ((size_t)bh * NSEQ + k0 + krow_p) * HD + hi4 * 8;
    size_t kr1 = kr0 + 4 * HD;
    bf16x8 kh0 = *(const bf16x8*)(kh + kr0);
    bf16x8 kh1 = *(const bf16x8*)(kh + kr1);
    bf16x8 kl0 = *(const bf16x8*)(kl + kr0);
    bf16x8 kl1 = *(const bf16x8*)(kl + kr1);
    bf16x8 vt0 = *(const bf16x8*)(vt + ((size_t)bh * HD +  0 + l16) * NSEQ + k0 + hi4 * 8);
    bf16x8 vt1 = *(const bf16x8*)(vt + ((size_t)bh * HD + 16 + l16) * NSEQ + k0 + hi4 * 8);

#pragma unroll
    for (int g = 0; g < 2; ++g) {
      f32x4 D0 = {0.f, 0.f, 0.f, 0.f};
      f32x4 D1 = {0.f, 0.f, 0.f, 0.f};
      D0 = __builtin_amdgcn_mfma_f32_16x16x32_bf16(kh0, qhf[g], D0, 0, 0, 0);
      D0 = __builtin_amdgcn_mfma_f32_16x16x32_bf16(kh0, qlf[g], D0, 0, 0, 0);
      D0 = __builtin_amdgcn_mfma_f32_16x16x32_bf16(kl0, qhf[g], D0, 0, 0, 0);
      D1 = __builtin_amdgcn_mfma_f32_16x16x32_bf16(kh1, qhf[g], D1, 0, 0, 0);
      D1 = __builtin_amdgcn_mfma_f32_16x16x32_bf16(kh1, qlf[g], D1, 0, 0, 0);
      D1 = __builtin_amdgcn_mfma_f32_16x16x32_bf16(kl1, qhf[g], D1, 0, 0, 0);

      bf16x8 b8 = *(const bf16x8*)(rb + ((size_t)h * NSEQ + qbase + g * 16 + l16) * NSEQ + k0 + hi4 * 8);

      float sv0[4], sv1[4];
#pragma unroll
      for (int r = 0; r < 4; ++r) {
        sv0[r] = D0[r] + bf2f((unsigned short)b8[r]);
        sv1[r] = D1[r] + bf2f((unsigned short)b8[4 + r]);
      }
      float tm = fmaxf(fmaxf(fmaxf(sv0[0], sv0[1]), fmaxf(sv0[2], sv0[3])),
                       fmaxf(fmaxf(sv1[0], sv1[1]), fmaxf(sv1[2], sv1[3])));
      tm = fmaxf(tm, __shfl_xor(tm, 16));
      tm = fmaxf(tm, __shfl_xor(tm, 32));
      float mn = fmaxf(mst[g], tm);
      float corr = __expf(mst[g] - mn);
      mst[g] = mn;
      float p0[4], p1[4], ps = 0.f;
#pragma unroll
      for (int r = 0; r < 4; ++r) {
        p0[r] = __expf(sv0[r] - mn);
        p1[r] = __expf(sv1[r] - mn);
        ps += p0[r] + p1[r];
      }
      ps += __shfl_xor(ps, 16);
      ps += __shfl_xor(ps, 32);
      lst[g] = lst[g] * corr + ps;

      float cA[4];
#pragma unroll
      for (int r = 0; r < 4; ++r) cA[r] = __shfl(corr, hi4 * 4 + r);
#pragma unroll
      for (int r = 0; r < 4; ++r) {
        accV[g][0][r] *= cA[r];
        accV[g][1][r] *= cA[r];
      }
      bf16x8 pa;
#pragma unroll
      for (int r = 0; r < 4; ++r) {
        pa[r]     = (short)f2bf(p0[r]);
        pa[4 + r] = (short)f2bf(p1[r]);
      }
      accV[g][0] = __builtin_amdgcn_mfma_f32_16x16x32_bf16(pa, vt0, accV[g][0], 0, 0, 0);
      accV[g][1] = __builtin_amdgcn_mfma_f32_16x16x32_bf16(pa, vt1, accV[g][1], 0, 0, 0);
    }
  }

#pragma unroll
  for (int g = 0; g < 2; ++g) {
    float inv = 1.f / lst[g];
    float iA[4];
#pragma unroll
    for (int r = 0; r < 4; ++r) iA[r] = __shfl(inv, hi4 * 4 + r);
#pragma unroll
    for (int df = 0; df < 2; ++df)
#pragma unroll
      for (int r = 0; r < 4; ++r) {
        size_t idx = ((size_t)b * NSEQ + qbase + g * 16 + hi4 * 4 + r) * DIMC
                     + h * HD + df * 16 + l16;
        float val = accV[g][df][r] * iA[r];
        unsigned short hh = f2bf(val);
        aoh[idx] = hh;
        aol[idx] = f2bf(val - bf2f(hh));
      }
  }
}

// ---------------------------------------------------------------------------
extern "C" void kernel_launch(void* const* d_in, const int* in_sizes, int n_in,
                              void* d_out, int out_size, void* d_ws, size_t ws_size,
                              hipStream_t stream)
{
  (void)in_sizes; (void)n_in; (void)out_size; (void)ws_size;
  const float* x      = (const float*)d_in[0];
  const float* qkv_w  = (const float*)d_in[1];
  const float* qkv_b  = (const float*)d_in[2];
  const float* proj_w = (const float*)d_in[3];
  const float* proj_b = (const float*)d_in[4];
  const float* temp   = (const float*)d_in[5];
  const float* qe     = (const float*)d_in[6];
  const float* fc1w   = (const float*)d_in[7];
  const float* fc1b   = (const float*)d_in[8];
  const float* fc2w   = (const float*)d_in[9];
  const float* fc2b   = (const float*)d_in[10];
  const float* tbl    = (const float*)d_in[11];
  const int*   rpi    = (const int*)d_in[12];
  const float* sls    = (const float*)d_in[13];
  // H=W=32 == trained resolution: both bilinear resizes are identity;
  // bias[h,n,m] = t[rpi[n*1024+m], h].

  char* ws = (char*)d_ws;
  const size_t perT = (size_t)BATCH * HEADS * NSEQ * HD;    // 4,194,304
  float* qb = (float*)ws;
  float* kb = qb + perT;
  float* vb = kb + perT;
  float* tT = vb + perT;                                    // 65536 f32 slot
  unsigned short* qh = (unsigned short*)(tT + 65536);
  unsigned short* ql = qh + perT;
  unsigned short* kh = ql + perT;
  unsigned short* kl = kh + perT;
  unsigned short* vt = kl + perT;
  unsigned short* xh = vt + perT;
  unsigned short* xl = xh + perT;
  unsigned short* pwh = xl + perT;                          // 262144
  unsigned short* pwl = pwh + 262144;
  // aliases (stream-ordered lifetimes):
  unsigned short* qwh = qh;              // dead before normsplit writes qh
  unsigned short* qwl = qh + 786432;     // fits inside qh's perT region
  unsigned short* rb  = (unsigned short*)qb;  // qb/kb dead after normsplit
  unsigned short* aoh = xh;              // xh/xl dead after gemm_qkv
  unsigned short* aol = xl;

  split_kernel<<<dim3(4096), 256, 0, stream>>>(x, xh, xl, 1048576);
  split_kernel<<<dim3(768),  256, 0, stream>>>(qkv_w, qwh, qwl, 196608);
  split_kernel<<<dim3(256),  256, 0, stream>>>(proj_w, pwh, pwl, 65536);
  gemm_split_kernel<0><<<dim3(12, 64), 256, 0, stream>>>(
      xh, xl, qwh, qwl, qkv_b, qb, kb, vb);
  cpb_kernel<<<dim3(TBLN), 256, 0, stream>>>(tbl, fc1w, fc1b, fc2w, fc2b, tT);
  normsplit_kernel<<<dim3((2*QROWS*32)/256), 256, 0, stream>>>(
      qb, kb, temp, qe, sls, qh, ql, kh, kl);
  vt_kernel<<<dim3(BATCH*HEADS, NSEQ/256), 256, 0, stream>>>(vb, vt);
  rb_gather_kernel<<<dim3((NSEQ*NSEQ)/256), 256, 0, stream>>>(tT, rpi, rb);
  attn_mfma_kernel<<<dim3(BATCH*HEADS, NSEQ/128), 256, 0, stream>>>(
      qh, ql, kh, kl, vt, rb, aoh, aol);
  gemm_split_kernel<1><<<dim3(4, 64), 256, 0, stream>>>(
      aoh, aol, pwh, pwl, proj_b, (float*)d_out, nullptr, nullptr);
}